// Round 5
// baseline (41.271 us; speedup 1.0000x reference)
//
#include <hip/hip_runtime.h>
#include <hip/hip_fp16.h>
#include <hip/hip_bf16.h>

#define OUTF 11008
#define INF  4096

typedef unsigned int uint;
typedef __attribute__((ext_vector_type(8))) short bf16x8;   // 8 bf16 = 4 VGPR (MFMA A/B)
typedef __attribute__((ext_vector_type(4))) float f32x4;    // MFMA C/D

union U4 { uint u[4]; bf16x8 v; };

__device__ __forceinline__ uint pack_bf162(float lo, float hi) {
  union { __hip_bfloat162 h; uint u; } cvt;
  cvt.h = __float22bfloat162_rn(make_float2(lo, hi));
  return cvt.u;
}

__global__ __launch_bounds__(512, 4) void lin2bit_kernel(
    const float* __restrict__ x, const int* __restrict__ wq,
    const float* __restrict__ wn, const float* __restrict__ bias,
    float* __restrict__ out)
{
  __shared__ float red[2048];        // 8 waves x 256 partials
  const int tid = threadIdx.x;
  const int wv  = tid >> 6;          // wave 0..7: K-split, groups [wv*16, wv*16+16)
  const int l   = tid & 63;
  const int col = l & 15;            // A-row (m) / B-col (o)
  const int q   = l >> 4;            // k-quad: lane covers k = 8q..8q+7 of each group
  const int o0  = (int)blockIdx.x << 4;

  const int    orow  = o0 + col;
  const size_t gbase = (size_t)orow * 128 + (size_t)(wv * 16);   // first group idx
  const char*  wp    = (const char*)wq + gbase * 32 + q * 8;      // 32 B per group
  const float* npr   = wn + gbase;                                // 16 norms (f32)
  const float* xp    = x + (size_t)col * INF + wv * 512 + q * 8;

  // ---- bulk prefetch of the cold weight stream: 16 x uint2, one latency
  uint2 pw[16];
#pragma unroll
  for (int j = 0; j < 16; ++j) pw[j] = *(const uint2*)(wp + j * 32);

  // ---- prefetch the 16 group norms (4 x float4)
  float n16[16];
#pragma unroll
  for (int c = 0; c < 4; ++c) {
    const float4 nv4 = *(const float4*)(npr + c * 4);
    n16[c * 4 + 0] = nv4.x; n16[c * 4 + 1] = nv4.y;
    n16[c * 4 + 2] = nv4.z; n16[c * 4 + 3] = nv4.w;
  }

  f32x4 acc = {0.f, 0.f, 0.f, 0.f};

#pragma unroll
  for (int j = 0; j < 16; ++j) {
    const uint2 p  = pw[j];
    const float nv  = n16[j];
    const float nv3 = nv * 0.333f;
    // 64-bit table: code c -> bf16 weight at bits [16c,16c+16): {-nv,-nv3,+nv3,+nv}
    const unsigned long long T =
        ((unsigned long long)pack_bf162(nv3, nv) << 32) |
        (unsigned long long)pack_bf162(-nv, -nv3);
    const uint p0 = p.x << 4, p1 = p.y << 4;
    const uint w0 = (uint)(T >> (p0 & 0x30u));
    const uint w1 = (uint)(T >> ((p0 >> 2) & 0x30u));
    const uint w2 = (uint)(T >> ((p0 >> 4) & 0x30u));
    const uint w3 = (uint)(T >> ((p0 >> 6) & 0x30u));
    const uint w4 = (uint)(T >> (p1 & 0x30u));
    const uint w5 = (uint)(T >> ((p1 >> 2) & 0x30u));
    const uint w6 = (uint)(T >> ((p1 >> 4) & 0x30u));
    const uint w7 = (uint)(T >> ((p1 >> 6) & 0x30u));
    U4 B;
    B.u[0] = (w0 & 0xFFFFu) | (w1 << 16);
    B.u[1] = (w2 & 0xFFFFu) | (w3 << 16);
    B.u[2] = (w4 & 0xFFFFu) | (w5 << 16);
    B.u[3] = (w6 & 0xFFFFu) | (w7 << 16);
    // A: x[m][same 8 k's], f32 -> bf16 (x is cache-hot: same 256 KB for all blocks)
    const float4 xa = *(const float4*)(xp + j * 32);
    const float4 xb = *(const float4*)(xp + j * 32 + 4);
    U4 A;
    A.u[0] = pack_bf162(xa.x, xa.y);
    A.u[1] = pack_bf162(xa.z, xa.w);
    A.u[2] = pack_bf162(xb.x, xb.y);
    A.u[3] = pack_bf162(xb.z, xb.w);
    acc = __builtin_amdgcn_mfma_f32_16x16x32_bf16(A.v, B.v, acc, 0, 0, 0);
  }

  // ---- cross-wave K reduction + bias + store
  red[wv * 256 +   0 + l] = acc[0];
  red[wv * 256 +  64 + l] = acc[1];
  red[wv * 256 + 128 + l] = acc[2];
  red[wv * 256 + 192 + l] = acc[3];
  __syncthreads();
  const int t = tid;
  if (t < 256) {
    float s = red[t];
#pragma unroll
    for (int w = 1; w < 8; ++w) s += red[w * 256 + t];
    const int m  = ((t & 63) >> 4) * 4 + ((t >> 6) & 3);  // D row = (lane>>4)*4 + reg
    const int oc = t & 15;                                 // D col = lane & 15
    out[(size_t)m * OUTF + o0 + oc] = s + bias[o0 + oc];
  }
}

extern "C" void kernel_launch(void* const* d_in, const int* in_sizes, int n_in,
                              void* d_out, int out_size, void* d_ws, size_t ws_size,
                              hipStream_t stream) {
  (void)in_sizes; (void)n_in; (void)out_size; (void)d_ws; (void)ws_size;
  const float* x    = (const float*)d_in[0];
  const int*   wq   = (const int*)d_in[1];
  const float* wn   = (const float*)d_in[2];
  const float* bias = (const float*)d_in[3];
  float*       out  = (float*)d_out;
  lin2bit_kernel<<<dim3(OUTF / 16), dim3(512), 0, stream>>>(x, wq, wn, bias, out);
}

// Round 6
// 27.379 us; speedup vs baseline: 1.5074x; 1.5074x over previous
//
#include <hip/hip_runtime.h>
#include <hip/hip_bf16.h>

#define OUTF 11008
#define INF  4096

typedef unsigned int uint;
typedef __attribute__((ext_vector_type(8))) short bf16x8;   // 8 bf16 = 4 VGPR (MFMA A/B)
typedef __attribute__((ext_vector_type(4))) float f32x4;    // MFMA C/D

typedef __attribute__((address_space(1))) void gvoid_t;
typedef __attribute__((address_space(3))) void svoid_t;

union U4 { uint u[4]; bf16x8 v; };

__device__ __forceinline__ uint pack_bf162(float lo, float hi) {
  union { __hip_bfloat162 h; uint u; } cvt;
  cvt.h = __float22bfloat162_rn(make_float2(lo, hi));
  return cvt.u;
}

// ---- pre-pack x (f32, row-major 16x4096) into MFMA A-fragment order, bf16.
// xpk[kblk][lane] = 16 B: lane (col=l&15, q=l>>4) holds x[col][kblk*32+q*8 .. +8]
__global__ __launch_bounds__(256) void pack_x_kernel(const float* __restrict__ x,
                                                     uint4* __restrict__ xpk) {
  const int t = (int)blockIdx.x * 256 + (int)threadIdx.x;   // 0..8191
  const int kblk = t >> 6, l = t & 63, col = l & 15, q = l >> 4;
  const float* src = x + (size_t)col * INF + kblk * 32 + q * 8;
  const float4 a = *(const float4*)src;
  const float4 b = *(const float4*)(src + 4);
  uint4 o;
  o.x = pack_bf162(a.x, a.y); o.y = pack_bf162(a.z, a.w);
  o.z = pack_bf162(b.x, b.y); o.w = pack_bf162(b.z, b.w);
  xpk[t] = o;
}

template <bool PACKED>
__global__ __launch_bounds__(512, 4) void lin2bit_kernel(
    const float* __restrict__ x, const uint4* __restrict__ xpk,
    const int* __restrict__ wq, const float* __restrict__ wn,
    const float* __restrict__ bias, float* __restrict__ out)
{
  __shared__ __align__(16) char lds[65536];   // 8 wave slabs x 8 KB; red overlaid later
  const int tid = threadIdx.x;
  const int wv  = tid >> 6;          // wave 0..7: K-split, groups [wv*16, wv*16+16)
  const int l   = tid & 63;
  const int col = l & 15;            // A-row (m) / B-col (o)
  const int q   = l >> 4;            // k-quad: lane covers k = 8q..8q+7 of each group
  const int o0  = (int)blockIdx.x << 4;

  char* wbuf = lds + wv * 8192;      // this wave's slab: addr(r,s,b) = r*512 + s*32 + b
                                     // content: slab[r][s] = group (wv*16 + (s^r)) of row o0+r

  // ---- 1) weight DMA: 8 x 1 KB global_load_lds, coalesced per-lane src, swizzled content
  {
    const int half = l >> 5;          // row parity within instruction
    const int s    = (l & 31) >> 1;   // slot 0..15
    const int b    = (l & 1) << 4;    // byte half of the 32 B group
#pragma unroll
    for (int i = 0; i < 8; ++i) {
      const int r = 2 * i + half;
      const char* src = (const char*)wq + (size_t)(o0 + r) * 4096
                        + (size_t)(wv * 16 + (s ^ r)) * 32 + b;
      __builtin_amdgcn_global_load_lds((gvoid_t*)src,
                                       (svoid_t*)(wbuf + i * 1024 + l * 16), 16, 0, 0);
    }
  }

  // ---- 2) A fragments into registers (issued before the fence -> stays in flight)
  U4 af[16];
  if constexpr (PACKED) {
#pragma unroll
    for (int j = 0; j < 16; ++j) *(uint4*)&af[j] = xpk[(wv * 16 + j) * 64 + l];
  } else {
    const float* xp = x + (size_t)col * INF + wv * 512 + q * 8;
#pragma unroll
    for (int j = 0; j < 16; ++j) {
      const float4 a = *(const float4*)(xp + j * 32);
      const float4 b = *(const float4*)(xp + j * 32 + 4);
      af[j].u[0] = pack_bf162(a.x, a.y); af[j].u[1] = pack_bf162(a.z, a.w);
      af[j].u[2] = pack_bf162(b.x, b.y); af[j].u[3] = pack_bf162(b.z, b.w);
    }
  }

  // ---- 3) norms (16 per lane row)
  float n16[16];
  {
    const float* npr = wn + (size_t)(o0 + col) * 128 + wv * 16;
#pragma unroll
    for (int c = 0; c < 4; ++c) {
      const float4 nv = *(const float4*)(npr + c * 4);
      n16[4*c+0] = nv.x; n16[4*c+1] = nv.y; n16[4*c+2] = nv.z; n16[4*c+3] = nv.w;
    }
  }

  // ---- fence: all VMEM above must be issued & complete; nothing may sink past
  asm volatile("s_waitcnt vmcnt(0)" ::: "memory");

  // ---- 4) compute: LDS + registers only
  f32x4 acc = {0.f, 0.f, 0.f, 0.f};
#pragma unroll
  for (int j = 0; j < 16; ++j) {
    const uint2 p = *(const uint2*)(wbuf + col * 512 + ((j ^ col) << 5) + q * 8);
    const float nv  = n16[j];
    const float nv3 = nv * 0.333f;
    // 64-bit table: code c -> bf16 weight at bits [16c,16c+16): {-nv,-nv3,+nv3,+nv}
    const unsigned long long T =
        ((unsigned long long)pack_bf162(nv3, nv) << 32) |
        (unsigned long long)pack_bf162(-nv, -nv3);
    const uint p0 = p.x << 4, p1 = p.y << 4;
    const uint w0 = (uint)(T >> (p0 & 0x30u));
    const uint w1 = (uint)(T >> ((p0 >> 2) & 0x30u));
    const uint w2 = (uint)(T >> ((p0 >> 4) & 0x30u));
    const uint w3 = (uint)(T >> ((p0 >> 6) & 0x30u));
    const uint w4 = (uint)(T >> (p1 & 0x30u));
    const uint w5 = (uint)(T >> ((p1 >> 2) & 0x30u));
    const uint w6 = (uint)(T >> ((p1 >> 4) & 0x30u));
    const uint w7 = (uint)(T >> ((p1 >> 6) & 0x30u));
    U4 B;
    B.u[0] = (w0 & 0xFFFFu) | (w1 << 16);
    B.u[1] = (w2 & 0xFFFFu) | (w3 << 16);
    B.u[2] = (w4 & 0xFFFFu) | (w5 << 16);
    B.u[3] = (w6 & 0xFFFFu) | (w7 << 16);
    acc = __builtin_amdgcn_mfma_f32_16x16x32_bf16(af[j].v, B.v, acc, 0, 0, 0);
  }

  // ---- 5) cross-wave K reduction (red overlays slab region; barrier first) + store
  __syncthreads();
  float* red = (float*)lds;          // 2048 floats = 8 KB
  red[wv * 256 +   0 + l] = acc[0];
  red[wv * 256 +  64 + l] = acc[1];
  red[wv * 256 + 128 + l] = acc[2];
  red[wv * 256 + 192 + l] = acc[3];
  __syncthreads();
  const int t = tid;
  if (t < 256) {
    float s = red[t];
#pragma unroll
    for (int w = 1; w < 8; ++w) s += red[w * 256 + t];
    const int m  = ((t & 63) >> 4) * 4 + (t >> 6);   // D row = (lane>>4)*4 + reg
    const int oc = t & 15;                            // D col = lane & 15
    out[(size_t)m * OUTF + o0 + oc] = s + bias[o0 + oc];
  }
}

extern "C" void kernel_launch(void* const* d_in, const int* in_sizes, int n_in,
                              void* d_out, int out_size, void* d_ws, size_t ws_size,
                              hipStream_t stream) {
  (void)in_sizes; (void)n_in; (void)out_size;
  const float* x    = (const float*)d_in[0];
  const int*   wq   = (const int*)d_in[1];
  const float* wn   = (const float*)d_in[2];
  const float* bias = (const float*)d_in[3];
  float*       out  = (float*)d_out;
  if (ws_size >= 131072) {
    uint4* xpk = (uint4*)d_ws;
    pack_x_kernel<<<dim3(32), dim3(256), 0, stream>>>(x, xpk);
    lin2bit_kernel<true><<<dim3(OUTF / 16), dim3(512), 0, stream>>>(x, xpk, wq, wn, bias, out);
  } else {
    lin2bit_kernel<false><<<dim3(OUTF / 16), dim3(512), 0, stream>>>(x, nullptr, wq, wn, bias, out);
  }
}

// Round 7
// 25.584 us; speedup vs baseline: 1.6132x; 1.0702x over previous
//
#include <hip/hip_runtime.h>
#include <hip/hip_fp16.h>
#include <hip/hip_bf16.h>

#define OUTF 11008
#define INF  4096

typedef unsigned int uint;
typedef __attribute__((ext_vector_type(8))) _Float16 f16x8;  // MFMA A/B (4 VGPR)
typedef __attribute__((ext_vector_type(4))) float f32x4;     // MFMA C/D

typedef __attribute__((address_space(1))) void gvoid_t;
typedef __attribute__((address_space(3))) void svoid_t;

union UA { uint4 u4; uint u[4]; f16x8 v; };
union UH { uint u; __half2 h; };

// ---- pre-pack x (f32 16x4096) -> f16 MFMA A-fragments.
// xpk[kblk*64+l] = lane l (col=l&15,q=l>>4) holds x[col][kblk*32+q*8 .. +8] as 8 f16
__global__ __launch_bounds__(256) void pack_x_kernel(const float* __restrict__ x,
                                                     uint4* __restrict__ xpk) {
  const int t = (int)blockIdx.x * 256 + (int)threadIdx.x;   // 0..8191
  const int kblk = t >> 6, l = t & 63, col = l & 15, q = l >> 4;
  const float* src = x + (size_t)col * INF + kblk * 32 + q * 8;
  const float4 a = *(const float4*)src;
  const float4 b = *(const float4*)(src + 4);
  UH c0, c1, c2, c3;
  c0.h = __floats2half2_rn(a.x, a.y);
  c1.h = __floats2half2_rn(a.z, a.w);
  c2.h = __floats2half2_rn(b.x, b.y);
  c3.h = __floats2half2_rn(b.z, b.w);
  xpk[t] = make_uint4(c0.u, c1.u, c2.u, c3.u);
}

#define WAITV(n) asm volatile("s_waitcnt vmcnt(" #n ")" ::: "memory")

__global__ __launch_bounds__(512, 4) void lin2bit_kernel(
    const uint4* __restrict__ xpk, const int* __restrict__ wq,
    const float* __restrict__ wn, const float* __restrict__ bias,
    float* __restrict__ out)
{
  // [0,2048): f16 dequant LUT. [2048,67584): 8 wave slabs x 8KB.
  // slab layout: slot s (0..15) * 512 + row r * 32 + byte b  (slot = K-group)
  __shared__ __align__(16) char lds[67584];
  const int tid = threadIdx.x;
  const int wv  = tid >> 6;          // wave 0..7: K-split, groups [wv*16, wv*16+16)
  const int l   = tid & 63;
  const int col = l & 15;            // A-row (m) / B-col (o)
  const int q   = l >> 4;            // lane covers k = 8q..8q+7 of each group
  const int o0  = (int)blockIdx.x << 4;

  // ---- build LUT: entry b = 4 unscaled f16 levels for the 4 codes of byte b
  if (tid < 256) {
    const unsigned short L[4] = {0xBC00u, 0xB555u, 0x3555u, 0x3C00u}; // -1,-.333,.333,1
    const uint lo = (uint)L[tid & 3]        | ((uint)L[(tid >> 2) & 3] << 16);
    const uint hi = (uint)L[(tid >> 4) & 3] | ((uint)L[(tid >> 6) & 3] << 16);
    *(uint2*)(lds + tid * 8) = make_uint2(lo, hi);
  }
  __syncthreads();   // drains only the LUT writes (before any DMA is issued)

  char* slab = lds + 2048 + wv * 8192;

  // ---- 1) x fragments: 16 coalesced dwordx4 (oldest VMEM in the vmcnt FIFO)
  UA af[16];
#pragma unroll
  for (int j = 0; j < 16; ++j) af[j].u4 = xpk[(wv * 16 + j) * 64 + l];

  // ---- 2) norms: 16 f32 for this lane's o-row
  float4 nf[4];
  {
    const float* npr = wn + (size_t)(o0 + col) * 128 + wv * 16;
#pragma unroll
    for (int c = 0; c < 4; ++c) nf[c] = *(const float4*)(npr + c * 4);
  }

  // ---- 3) weight DMA: 8 x 1KB; instr i carries K-slots {2i,2i+1} x 16 rows
  {
    const int r = (l >> 1) & 15, half = l & 1, s_lo = l >> 5;
    const char* src0 = (const char*)wq + (size_t)(o0 + r) * 4096
                       + (size_t)(wv * 16 + s_lo) * 32 + half * 16;
    char* dst0 = slab + l * 16;     // l = s_lo*32 + r*2 + half -> s_lo*512+r*32+half*16
#pragma unroll
    for (int i = 0; i < 8; ++i)
      __builtin_amdgcn_global_load_lds((gvoid_t*)(src0 + i * 64),
                                       (svoid_t*)(dst0 + i * 1024), 16, 0, 0);
  }

  // ---- x+norms retired; 8 weight DMAs still in flight. cvt hides DMA latency.
  WAITV(8);
  __half2 nv2[16];
#pragma unroll
  for (int c = 0; c < 4; ++c) {
    nv2[4*c+0] = __floats2half2_rn(nf[c].x, nf[c].x);
    nv2[4*c+1] = __floats2half2_rn(nf[c].y, nf[c].y);
    nv2[4*c+2] = __floats2half2_rn(nf[c].z, nf[c].z);
    nv2[4*c+3] = __floats2half2_rn(nf[c].w, nf[c].w);
  }

  f32x4 acc = {0.f, 0.f, 0.f, 0.f};
  const char* wr   = slab + col * 32 + q * 8;
  const char* lutb = lds;

#define STEP(j) { \
    const uint2 p  = *(const uint2*)(wr + (j) * 512); \
    const uint2 e0 = *(const uint2*)(lutb + ((size_t)p.x << 3)); \
    const uint2 e1 = *(const uint2*)(lutb + ((size_t)p.y << 3)); \
    UH a0, a1, a2, a3, b0, b1, b2, b3; \
    a0.u = e0.x; a1.u = e0.y; a2.u = e1.x; a3.u = e1.y; \
    b0.h = __hmul2(a0.h, nv2[j]); b1.h = __hmul2(a1.h, nv2[j]); \
    b2.h = __hmul2(a2.h, nv2[j]); b3.h = __hmul2(a3.h, nv2[j]); \
    UA B; B.u[0] = b0.u; B.u[1] = b1.u; B.u[2] = b2.u; B.u[3] = b3.u; \
    acc = __builtin_amdgcn_mfma_f32_16x16x32_f16(af[j].v, B.v, acc, 0, 0, 0); }

  // counted-vmcnt consume ladder: chunk c ready when outstanding <= 7-c
  WAITV(7); STEP(0)  STEP(1)
  WAITV(6); STEP(2)  STEP(3)
  WAITV(5); STEP(4)  STEP(5)
  WAITV(4); STEP(6)  STEP(7)
  WAITV(3); STEP(8)  STEP(9)
  WAITV(2); STEP(10) STEP(11)
  WAITV(1); STEP(12) STEP(13)
  WAITV(0); STEP(14) STEP(15)
#undef STEP

  // ---- cross-wave K reduction (red overlays LUT+slab region after barrier) + store
  __syncthreads();
  float* red = (float*)lds;          // 2048 floats = 8 KB
  red[wv * 256 +   0 + l] = acc[0];
  red[wv * 256 +  64 + l] = acc[1];
  red[wv * 256 + 128 + l] = acc[2];
  red[wv * 256 + 192 + l] = acc[3];
  __syncthreads();
  const int t = tid;
  if (t < 256) {
    float s = red[t];
#pragma unroll
    for (int w = 1; w < 8; ++w) s += red[w * 256 + t];
    const int m  = ((t & 63) >> 4) * 4 + (t >> 6);   // D row = (lane>>4)*4 + reg
    const int oc = t & 15;                            // D col = lane & 15
    out[(size_t)m * OUTF + o0 + oc] = s + bias[o0 + oc];
  }
}

extern "C" void kernel_launch(void* const* d_in, const int* in_sizes, int n_in,
                              void* d_out, int out_size, void* d_ws, size_t ws_size,
                              hipStream_t stream) {
  (void)in_sizes; (void)n_in; (void)out_size; (void)ws_size;
  const float* x    = (const float*)d_in[0];
  const int*   wq   = (const int*)d_in[1];
  const float* wn   = (const float*)d_in[2];
  const float* bias = (const float*)d_in[3];
  float*       out  = (float*)d_out;
  uint4*       xpk  = (uint4*)d_ws;   // 128 KB of workspace
  pack_x_kernel<<<dim3(32), dim3(256), 0, stream>>>(x, xpk);
  lin2bit_kernel<<<dim3(OUTF / 16), dim3(512), 0, stream>>>(xpk, wq, wn, bias, out);
}